// Round 14
// baseline (28.077 us; speedup 1.0000x reference)
//
#include <hip/hip_runtime.h>
#include <math.h>

#define NSPL 128
#define SCALE 512.0f

__device__ __forceinline__ float fast_cbrt_pos(float x) {
    // x >= 0. 2^(log2(x)/3) + one Newton step (~1-2 ulp). Value path only.
    float r  = __builtin_amdgcn_exp2f(__builtin_amdgcn_logf(x) * (1.0f/3.0f));
    float r2 = r * r;
    r = fmaf(0.33333333f, fmaf(x, __builtin_amdgcn_rcpf(r2), -r), r);
    return (x < 1e-35f) ? 0.0f : r;
}

// cos/sin on [0, pi/3] via Taylor-Horner (abs err <= 4e-8). r13-proven.
__device__ __forceinline__ float cos_small(float v) {
    const float v2 = v * v;
    float p = -2.7557319e-7f;
    p = fmaf(p, v2, 2.4801587e-5f);
    p = fmaf(p, v2, -1.3888889e-3f);
    p = fmaf(p, v2, 4.1666667e-2f);
    p = fmaf(p, v2, -0.5f);
    return fmaf(p, v2, 1.0f);
}
__device__ __forceinline__ float sin_small(float v) {
    const float v2 = v * v;
    float p = 2.7557319e-6f;
    p = fmaf(p, v2, -1.9841270e-4f);
    p = fmaf(p, v2, 8.3333333e-3f);
    p = fmaf(p, v2, -0.16666667f);
    return v * fmaf(p, v2, 1.0f);
}

// One kept-spline contribution for one pixel (r13 numerics, bit-identical).
__device__ __forceinline__ float eval_one(
    float py, float px, const float4 f0, const float4 f1,
    const float4 f2, const float4 lw4)
{
    const float Ay = f0.z, Ax = f0.w;
    const float By = f1.x, Bx = f1.y;
    const float ca27 = f1.z, ca3 = f1.w;
    const float twoax2 = f2.x, third = f2.y, cbK = f2.z, r_nB = f2.w;

    const float Cy = py - f0.x, Cx = px - f0.y;
    const float CdB = Cy*By + Cx*Bx;
    const float CdA = Cy*Ay + Cx*Ax;
    const float cb = (CdB - cbK) * r_nB;
    const float cc = CdA * r_nB;

    const float p_  = cb - third;
    const float p3  = p_ * p_ * p_;
    const float q   = fmaf(ca27, fmaf(-9.0f, cb, twoax2), cc);
    const float d   = fmaf(q, q, p3 * (4.0f/27.0f));

    const bool sgl = d > 0.0f;
    // single-root via Cardano identity (r12-proven)
    const float sd = __builtin_amdgcn_sqrtf(fmaxf(d, 0.0f));
    const float mm = (fabsf(q) + sd) * 0.5f;
    const float r  = fast_cbrt_pos(mm);
    const float sg = (q > 0.0f) ? -1.0f : 1.0f;
    const float r0 = fmaf(sg, fmaf(-p_ * 0.33333334f, __builtin_amdgcn_rcpf(r), r), -ca3);

    float T0 = r0, T1 = r0;
    const unsigned long long bd = __ballot(sgl);
    if (bd != ~0ull) {  // trig branch: acos path libm-verbatim; cos/sin poly
        const float p3s = (fabsf(p3) > 1e-9f) ? p3 : 1e-9f;
        const float aarg = -sqrtf(fmaxf(-27.0f / p3s, 0.0f)) * q * 0.5f;
        const float v = acosf(fminf(fmaxf(aarg, -1.0f), 1.0f)) / 3.0f;
        const float m = cos_small(v);
        const float nn = sin_small(v) * 1.7320508075688772f;
        const float sp = sqrtf(fmaxf(-p_ / 3.0f, 0.0f));
        const float r1 = (m + m) * sp - ca3;
        const float r2 = (-nn - m) * sp - ca3;
        if (!sgl) { T0 = r1; T1 = r2; }
    }
    T0 = fminf(fmaxf(T0, 0.0f), 1.0f);
    T1 = fminf(fmaxf(T1, 0.0f), 1.0f);

    const float Dy = Ay + Ay, Dx = Ax + Ax;
    const float d1y = (Dy + By*T0)*T0 - Cy, d1x = (Dx + Bx*T0)*T0 - Cx;
    const float d2y = (Dy + By*T1)*T1 - Cy, d2x = (Dx + Bx*T1)*T1 - Cx;
    const float q1 = d1y*d1y + d1x*d1x;
    const float q2 = d2y*d2y + d2x*d2x;
    const float dist = __builtin_amdgcn_sqrtf(fminf(q1, q2));

    const float sarg = (lw4.z - dist) * lw4.y;
    const float e = __builtin_amdgcn_exp2f(sarg * -1.4426950408889634f);
    return lw4.x * __builtin_amdgcn_rcpf(1.0f + e);
}

// ---------------- workspace layout: 9 x float4[128] tables (18 KB) ----------
// mm @0, eb @2048, sa @4096, sb @6144, sc @8192, f0 @10240, f1 @12288,
// f2 @14336, lw @16384

// Stage once: 1 block x 128 threads; same fp expressions as r13 staging.
__global__ __launch_bounds__(128) void stage_k(
    const float* __restrict__ ga, const float* __restrict__ gb,
    const float* __restrict__ gc, const float* __restrict__ glw,
    const float* __restrict__ glc, float4* __restrict__ ws)
{
    const int n = threadIdx.x;
    float4* g_mm = ws;
    float4* g_eb = ws + 128;
    float4* g_sa = ws + 256;
    float4* g_sb = ws + 384;
    float4* g_sc = ws + 512;
    float4* g_f0 = ws + 640;
    float4* g_f1 = ws + 768;
    float4* g_f2 = ws + 896;
    float4* g_lw = ws + 1024;

    const float ay  = ga[2*n],  ax  = ga[2*n+1];
    const float by_ = gb[2*n],  bx_ = gb[2*n+1];
    const float cy  = gc[2*n],  cx  = gc[2*n+1];
    const float w   = glw[n];

    // ---- reference _bbox_mask px bounds, round-4 verbatim ----
    float miy = fminf(ay, cy), may = fmaxf(ay, cy);
    float mix = fminf(ax, cx), maxx = fmaxf(ax, cx);
    bool cond = (by_ < miy) || (by_ > may) || (bx_ < mix) || (bx_ > maxx);
    float dny = ay - 2.0f*by_ + cy;
    float dnx = ax - 2.0f*bx_ + cx;
    bool dok = (fabsf(dny) > 1e-9f) && (fabsf(dnx) > 1e-9f);
    float tty = fminf(fmaxf((ay - by_) / ((fabsf(dny) > 1e-9f) ? dny : 1e-9f), 0.0f), 1.0f);
    float ttx = fminf(fmaxf((ax - bx_) / ((fabsf(dnx) > 1e-9f) ? dnx : 1e-9f), 0.0f), 1.0f);
    float sy = 1.0f - tty, sx = 1.0f - ttx;
    float qqy = sy*sy*ay + 2.0f*sy*tty*by_ + tty*tty*cy;
    float qqx = sx*sx*ax + 2.0f*sx*ttx*bx_ + ttx*ttx*cx;
    if (cond && dok) {
        miy = fminf(miy, qqy); may = fmaxf(may, qqy);
        mix = fminf(mix, qqx); maxx = fmaxf(maxx, qqx);
    }
    float mg = floorf(3.0f * w);   // MARGIN = 0
    float mi_py = fminf(fmaxf(floorf(miy*SCALE) - mg, 0.0f), 512.0f);
    float ma_py = fminf(fmaxf(ceilf (may*SCALE) + mg, 0.0f), 512.0f);
    float mi_px = fminf(fmaxf(floorf(mix*SCALE) - mg, 0.0f), 512.0f);
    float ma_px = fminf(fmaxf(ceilf (maxx*SCALE) + mg, 0.0f), 512.0f);
    g_mm[n] = make_float4(mi_py, ma_py, mi_px, ma_px);

    float bby = by_ + 1e-5f, bbx = bx_ + 1e-5f;
    float Ay = bby - ay, Ax = bbx - ax;
    float By = cy - bby - Ay, Bx = cx - bbx - Ax;
    float BdB = By*By + Bx*Bx;
    float nB  = -BdB;
    float AdB = Ay*By + Ax*Bx;
    float ca  = (-3.0f * AdB) / nB;
    float ax2 = ca * ca;
    g_f0[n] = make_float4(ay, ax, Ay, Ax);
    g_f1[n] = make_float4(By, Bx, ca / 27.0f, ca / 3.0f);
    g_f2[n] = make_float4(2.0f * ax2, ax2 / 3.0f,
                          2.0f * (Ay*Ay + Ax*Ax), 1.0f / nB);
    g_lw[n] = make_float4(glc[n], 6.0f / w, w, 0.0f);

    // expanded bbox (E px): beyond E each contribution < 1.2e-5
    float E = fmaf(2.9f * 512.0f, w, 3.0f);
    g_eb[n] = make_float4(mi_py - E, ma_py + E, mi_px - E, ma_px + E);

    // chord-band: curve t=0,.25,.5,.75,1 in px; quarter-chord dev <= |B|*511/64
    float q0y = ay * 511.0f,                                   q0x = ax * 511.0f;
    float q1y = (ay + 2.0f*Ay*0.25f + By*0.0625f) * 511.0f,    q1x = (ax + 2.0f*Ax*0.25f + Bx*0.0625f) * 511.0f;
    float q2y = (ay + Ay + By*0.25f) * 511.0f,                 q2x = (ax + Ax + Bx*0.25f) * 511.0f;
    float q3y = (ay + 2.0f*Ay*0.75f + By*0.5625f) * 511.0f,    q3x = (ax + 2.0f*Ax*0.75f + Bx*0.5625f) * 511.0f;
    float q4y = (ay + 2.0f*Ay + By) * 511.0f,                  q4x = (ax + 2.0f*Ax + Bx) * 511.0f;
    float dev = __builtin_amdgcn_sqrtf(BdB) * (511.0f / 64.0f);
    float R   = E + dev + 6.0f;   // + halfdiag(5.66) + slop
    g_sa[n] = make_float4(q0y, q0x, q1y, q1x);
    g_sb[n] = make_float4(q2y, q2x, q3y, q3x);
    g_sc[n] = make_float4(q4y, q4x, R * R, 0.0f);
}

// Render: 4096 blocks x 64 threads; block = one 8x8-px region. Tables are
// L1-resident (18 KB). HW dispatcher load-balances at block granularity.
// Filter: tile flag (from mm, r9-identical) && ebox && chord-band; eval r13.
__global__ __launch_bounds__(64) void render_k(
    const float4* __restrict__ ws, float* __restrict__ out)
{
    const float4* g_mm = ws;
    const float4* g_eb = ws + 128;
    const float4* g_sa = ws + 256;
    const float4* g_sb = ws + 384;
    const float4* g_sc = ws + 512;
    const float4* g_f0 = ws + 640;
    const float4* g_f1 = ws + 768;
    const float4* g_f2 = ws + 896;
    const float4* g_lw = ws + 1024;

    __shared__ int s_wl[NSPL];
    const int lane = threadIdx.x;
    const int rx = blockIdx.x & 63, ry = blockIdx.x >> 6;   // 8x8-px region
    const float wy0f = (float)(ry << 3), wx0f = (float)(rx << 3);
    const float ty0 = (float)((ry >> 3) << 6);              // enclosing tile
    const float tx0 = (float)((rx >> 3) << 6);
    const float cyp = wy0f + 3.5f, cxp = wx0f + 3.5f;       // region center

    int cnt = 0;
    #pragma unroll
    for (int h = 0; h < 2; ++h) {
        const int n = (h << 6) + lane;
        const float4 mm = g_mm[n];
        const float4 eb = g_eb[n];
        bool keep = (mm.y > ty0) && (mm.x < ty0 + 64.0f)
                 && (mm.w > tx0) && (mm.z < tx0 + 64.0f)
                 && (eb.y > wy0f) && (eb.x < wy0f + 8.0f)
                 && (eb.w > wx0f) && (eb.z < wx0f + 8.0f);
        if (keep) {
            const float4 sa = g_sa[n];
            const float4 sb = g_sb[n];
            const float4 sc = g_sc[n];
            float best = 1e30f;
            float py0 = sa.x, px0 = sa.y;
            #pragma unroll
            for (int s = 0; s < 4; ++s) {
                const float py1 = (s == 0) ? sa.z : (s == 1) ? sb.x : (s == 2) ? sb.z : sc.x;
                const float px1 = (s == 0) ? sa.w : (s == 1) ? sb.y : (s == 2) ? sb.w : sc.y;
                const float vy = py1 - py0, vx = px1 - px0;
                const float wy = cyp - py0, wx = cxp - px0;
                const float vv = fmaxf(vy*vy + vx*vx, 1e-12f);
                const float tt = fminf(fmaxf((wy*vy + wx*vx) * __builtin_amdgcn_rcpf(vv), 0.0f), 1.0f);
                const float dy = wy - tt*vy, dx = wx - tt*vx;
                best = fminf(best, dy*dy + dx*dx);
                py0 = py1; px0 = px1;
            }
            keep = best <= sc.z;
        }
        const unsigned long long b = __ballot(keep);
        const int pos = cnt + __popcll(b & ((1ull << lane) - 1ull));
        if (keep) s_wl[pos] = n;
        cnt += __popcll(b);
    }
    __syncthreads();   // single wave: orders LDS writes before reads

    const int px_i = (rx << 3) + (lane & 7);
    const int py_i = (ry << 3) + (lane >> 3);
    const float py = (float)py_i * (1.0f / 511.0f);
    const float px = (float)px_i * (1.0f / 511.0f);

    float sum = 0.0f;
    int i = 0;
    for (; i + 3 <= cnt; i += 3) {
        const int n0 = s_wl[i];
        const int n1 = s_wl[i+1];
        const int n2 = s_wl[i+2];
        const float c_0 = eval_one(py, px, g_f0[n0], g_f1[n0], g_f2[n0], g_lw[n0]);
        const float c_1 = eval_one(py, px, g_f0[n1], g_f1[n1], g_f2[n1], g_lw[n1]);
        const float c_2 = eval_one(py, px, g_f0[n2], g_f1[n2], g_f2[n2], g_lw[n2]);
        sum = ((sum + c_0) + c_1) + c_2;     // ascending order preserved
    }
    for (; i < cnt; ++i) {
        const int n0 = s_wl[i];
        sum += eval_one(py, px, g_f0[n0], g_f1[n0], g_f2[n0], g_lw[n0]);
    }

    out[py_i * 512 + px_i] = 1.0f - sum;
}

extern "C" void kernel_launch(void* const* d_in, const int* in_sizes, int n_in,
                              void* d_out, int out_size, void* d_ws, size_t ws_size,
                              hipStream_t stream) {
    const float* a  = (const float*)d_in[0];
    const float* b  = (const float*)d_in[1];
    const float* c  = (const float*)d_in[2];
    const float* lw = (const float*)d_in[3];
    const float* lc = (const float*)d_in[4];
    float* out = (float*)d_out;
    float4* ws = (float4*)d_ws;

    stage_k<<<dim3(1), dim3(128), 0, stream>>>(a, b, c, lw, lc, ws);
    render_k<<<dim3(4096), dim3(64), 0, stream>>>(ws, out);
}

// Round 15
// 21.454 us; speedup vs baseline: 1.3087x; 1.3087x over previous
//
#include <hip/hip_runtime.h>
#include <math.h>

#define NSPL 128
#define SCALE 512.0f

__device__ __forceinline__ float fast_cbrt_pos(float x) {
    // x >= 0. 2^(log2(x)/3) + one Newton step (~1-2 ulp). Value path only.
    float r  = __builtin_amdgcn_exp2f(__builtin_amdgcn_logf(x) * (1.0f/3.0f));
    float r2 = r * r;
    r = fmaf(0.33333333f, fmaf(x, __builtin_amdgcn_rcpf(r2), -r), r);
    return (x < 1e-35f) ? 0.0f : r;
}

// cos/sin on [0, pi/3] via Taylor-Horner (abs err <= 4e-8). r13-proven.
__device__ __forceinline__ float cos_small(float v) {
    const float v2 = v * v;
    float p = -2.7557319e-7f;
    p = fmaf(p, v2, 2.4801587e-5f);
    p = fmaf(p, v2, -1.3888889e-3f);
    p = fmaf(p, v2, 4.1666667e-2f);
    p = fmaf(p, v2, -0.5f);
    return fmaf(p, v2, 1.0f);
}
__device__ __forceinline__ float sin_small(float v) {
    const float v2 = v * v;
    float p = 2.7557319e-6f;
    p = fmaf(p, v2, -1.9841270e-4f);
    p = fmaf(p, v2, 8.3333333e-3f);
    p = fmaf(p, v2, -0.16666667f);
    return v * fmaf(p, v2, 1.0f);
}

// One kept-spline contribution for one pixel (r13 numerics, bit-identical).
__device__ __forceinline__ float eval_one(
    float py, float px, const float4 f0, const float4 f1,
    const float4 f2, const float4 lw4)
{
    const float Ay = f0.z, Ax = f0.w;
    const float By = f1.x, Bx = f1.y;
    const float ca27 = f1.z, ca3 = f1.w;
    const float twoax2 = f2.x, third = f2.y, cbK = f2.z, r_nB = f2.w;

    const float Cy = py - f0.x, Cx = px - f0.y;
    const float CdB = Cy*By + Cx*Bx;
    const float CdA = Cy*Ay + Cx*Ax;
    const float cb = (CdB - cbK) * r_nB;
    const float cc = CdA * r_nB;

    const float p_  = cb - third;
    const float p3  = p_ * p_ * p_;
    const float q   = fmaf(ca27, fmaf(-9.0f, cb, twoax2), cc);
    const float d   = fmaf(q, q, p3 * (4.0f/27.0f));

    const bool sgl = d > 0.0f;
    // single-root via Cardano identity (r12-proven)
    const float sd = __builtin_amdgcn_sqrtf(fmaxf(d, 0.0f));
    const float mm = (fabsf(q) + sd) * 0.5f;
    const float r  = fast_cbrt_pos(mm);
    const float sg = (q > 0.0f) ? -1.0f : 1.0f;
    const float r0 = fmaf(sg, fmaf(-p_ * 0.33333334f, __builtin_amdgcn_rcpf(r), r), -ca3);

    float T0 = r0, T1 = r0;
    const unsigned long long bd = __ballot(sgl);
    if (bd != ~0ull) {  // trig branch: acos path libm-verbatim; cos/sin poly
        const float p3s = (fabsf(p3) > 1e-9f) ? p3 : 1e-9f;
        const float aarg = -sqrtf(fmaxf(-27.0f / p3s, 0.0f)) * q * 0.5f;
        const float v = acosf(fminf(fmaxf(aarg, -1.0f), 1.0f)) / 3.0f;
        const float m = cos_small(v);
        const float nn = sin_small(v) * 1.7320508075688772f;
        const float sp = sqrtf(fmaxf(-p_ / 3.0f, 0.0f));
        const float r1 = (m + m) * sp - ca3;
        const float r2 = (-nn - m) * sp - ca3;
        if (!sgl) { T0 = r1; T1 = r2; }
    }
    T0 = fminf(fmaxf(T0, 0.0f), 1.0f);
    T1 = fminf(fmaxf(T1, 0.0f), 1.0f);

    const float Dy = Ay + Ay, Dx = Ax + Ax;
    const float d1y = (Dy + By*T0)*T0 - Cy, d1x = (Dx + Bx*T0)*T0 - Cx;
    const float d2y = (Dy + By*T1)*T1 - Cy, d2x = (Dx + Bx*T1)*T1 - Cx;
    const float q1 = d1y*d1y + d1x*d1x;
    const float q2 = d2y*d2y + d2x*d2x;
    const float dist = __builtin_amdgcn_sqrtf(fminf(q1, q2));

    const float sarg = (lw4.z - dist) * lw4.y;
    const float e = __builtin_amdgcn_exp2f(sarg * -1.4426950408889634f);
    return lw4.x * __builtin_amdgcn_rcpf(1.0f + e);
}

// 1024 blocks x 512 threads; block = 16x16 px. Waves 0-3: quadrant q, FIRST
// half of kept list; waves 4-7: quadrant q, SECOND half. Dense-region critical
// path halves. total = firstHalf + secondHalf (single reassociation, ~1e-6).
__global__ __launch_bounds__(512) void spline_render(
    const float* __restrict__ ga, const float* __restrict__ gb,
    const float* __restrict__ gc, const float* __restrict__ glw,
    const float* __restrict__ glc, float* __restrict__ out)
{
    __shared__ float4 s_f0[NSPL], s_f1[NSPL], s_f2[NSPL], s_eb[NSPL];
    __shared__ float4 s_sa[NSPL], s_sb[NSPL], s_sc[NSPL];
    __shared__ float4 s_lw[NSPL];
    __shared__ int    s_wl[4][NSPL];
    __shared__ int    s_cnt[4];
    __shared__ float  s_part[4][64];

    const int t  = threadIdx.x;
    const int bx = blockIdx.x & 31;   // 32 blocks across (16 px each)
    const int by = blockIdx.x >> 5;   // 32 blocks down  (16 px each)
    const float ty0 = (float)((by >> 2) << 6);   // enclosing 64x64 tile
    const float tx0 = (float)((bx >> 2) << 6);

    if (t < NSPL) {
        // ---- round-4 mask + constants, verbatim values ----
        const int n = t;
        const float ay  = ga[2*n],  ax  = ga[2*n+1];
        const float by_ = gb[2*n],  bx_ = gb[2*n+1];
        const float cy  = gc[2*n],  cx  = gc[2*n+1];
        const float w   = glw[n];

        float miy = fminf(ay, cy), may = fmaxf(ay, cy);
        float mix = fminf(ax, cx), maxx = fmaxf(ax, cx);
        bool cond = (by_ < miy) || (by_ > may) || (bx_ < mix) || (bx_ > maxx);
        float dny = ay - 2.0f*by_ + cy;
        float dnx = ax - 2.0f*bx_ + cx;
        bool dok = (fabsf(dny) > 1e-9f) && (fabsf(dnx) > 1e-9f);
        float tty = fminf(fmaxf((ay - by_) / ((fabsf(dny) > 1e-9f) ? dny : 1e-9f), 0.0f), 1.0f);
        float ttx = fminf(fmaxf((ax - bx_) / ((fabsf(dnx) > 1e-9f) ? dnx : 1e-9f), 0.0f), 1.0f);
        float sy = 1.0f - tty, sx = 1.0f - ttx;
        float qqy = sy*sy*ay + 2.0f*sy*tty*by_ + tty*tty*cy;
        float qqx = sx*sx*ax + 2.0f*sx*ttx*bx_ + ttx*ttx*cx;
        if (cond && dok) {
            miy = fminf(miy, qqy); may = fmaxf(may, qqy);
            mix = fminf(mix, qqx); maxx = fmaxf(maxx, qqx);
        }
        float mg = floorf(3.0f * w);   // MARGIN = 0
        float mi_py = fminf(fmaxf(floorf(miy*SCALE) - mg, 0.0f), 512.0f);
        float ma_py = fminf(fmaxf(ceilf (may*SCALE) + mg, 0.0f), 512.0f);
        float mi_px = fminf(fmaxf(floorf(mix*SCALE) - mg, 0.0f), 512.0f);
        float ma_px = fminf(fmaxf(ceilf (maxx*SCALE) + mg, 0.0f), 512.0f);
        bool flag = (ma_py > ty0) && (mi_py < ty0 + 64.0f)
                 && (ma_px > tx0) && (mi_px < tx0 + 64.0f);

        float bby = by_ + 1e-5f, bbx = bx_ + 1e-5f;
        float Ay = bby - ay, Ax = bbx - ax;
        float By = cy - bby - Ay, Bx = cx - bbx - Ax;
        float BdB = By*By + Bx*Bx;
        float nB  = -BdB;
        float AdB = Ay*By + Ax*Bx;
        float ca  = (-3.0f * AdB) / nB;
        float ax2 = ca * ca;
        s_f0[n] = make_float4(ay, ax, Ay, Ax);
        s_f1[n] = make_float4(By, Bx, ca / 27.0f, ca / 3.0f);
        s_f2[n] = make_float4(2.0f * ax2, ax2 / 3.0f,
                              2.0f * (Ay*Ay + Ax*Ax), 1.0f / nB);
        s_lw[n] = make_float4(glc[n], 6.0f / w, w, 0.0f);

        // expanded bbox (E px): beyond E each contribution < 1.2e-5
        float E = fmaf(2.9f * 512.0f, w, 3.0f);
        s_eb[n] = flag ? make_float4(mi_py - E, ma_py + E, mi_px - E, ma_px + E)
                       : make_float4(1e30f, -1e30f, 1e30f, -1e30f);

        // chord-band data: curve(t) = a + 2At + Bt^2, t=0,.25,.5,.75,1 in px;
        // per-quarter-chord deviation <= |B|*511/64.
        float q0y = ay * 511.0f,                                   q0x = ax * 511.0f;
        float q1y = (ay + 2.0f*Ay*0.25f + By*0.0625f) * 511.0f,    q1x = (ax + 2.0f*Ax*0.25f + Bx*0.0625f) * 511.0f;
        float q2y = (ay + Ay + By*0.25f) * 511.0f,                 q2x = (ax + Ax + Bx*0.25f) * 511.0f;
        float q3y = (ay + 2.0f*Ay*0.75f + By*0.5625f) * 511.0f,    q3x = (ax + 2.0f*Ax*0.75f + Bx*0.5625f) * 511.0f;
        float q4y = (ay + 2.0f*Ay + By) * 511.0f,                  q4x = (ax + 2.0f*Ax + Bx) * 511.0f;
        float dev = __builtin_amdgcn_sqrtf(BdB) * (511.0f / 64.0f);
        float R   = E + dev + 6.0f;   // + halfdiag(4.95) + slop
        s_sa[n] = make_float4(q0y, q0x, q1y, q1x);
        s_sb[n] = make_float4(q2y, q2x, q3y, q3x);
        s_sc[n] = make_float4(q4y, q4x, R * R, 0.0f);
    }
    __syncthreads();

    const int lane = t & 63;
    const int w8   = t >> 6;          // 0..7
    const int wv   = w8 & 3;          // quadrant
    const int half = w8 >> 2;         // 0: first half, 1: second half
    const int wx0 = (bx << 4) + ((wv & 1) << 3);
    const int wy0 = (by << 4) + ((wv >> 1) << 3);
    const float wy0f = (float)wy0, wx0f = (float)wx0;

    // ---- filter: waves 0-3 only (r13-identical values) ----
    if (half == 0) {
        const float cyp = wy0f + 3.5f, cxp = wx0f + 3.5f;
        int cnt = 0;
        #pragma unroll
        for (int h = 0; h < 2; ++h) {
            const int n = (h << 6) + lane;
            const float4 eb = s_eb[n];
            bool keep = (eb.y > wy0f) && (eb.x < wy0f + 8.0f)
                     && (eb.w > wx0f) && (eb.z < wx0f + 8.0f);
            if (keep) {
                const float4 sa = s_sa[n];
                const float4 sb = s_sb[n];
                const float4 sc = s_sc[n];
                float best = 1e30f;
                float py0 = sa.x, px0 = sa.y;
                #pragma unroll
                for (int s = 0; s < 4; ++s) {
                    const float py1 = (s == 0) ? sa.z : (s == 1) ? sb.x : (s == 2) ? sb.z : sc.x;
                    const float px1 = (s == 0) ? sa.w : (s == 1) ? sb.y : (s == 2) ? sb.w : sc.y;
                    const float vy = py1 - py0, vx = px1 - px0;
                    const float wy = cyp - py0, wx = cxp - px0;
                    const float vv = fmaxf(vy*vy + vx*vx, 1e-12f);
                    const float tt = fminf(fmaxf((wy*vy + wx*vx) * __builtin_amdgcn_rcpf(vv), 0.0f), 1.0f);
                    const float dy = wy - tt*vy, dx = wx - tt*vx;
                    best = fminf(best, dy*dy + dx*dx);
                    py0 = py1; px0 = px1;
                }
                keep = best <= sc.z;
            }
            const unsigned long long b = __ballot(keep);
            const int pos = cnt + __popcll(b & ((1ull << lane) - 1ull));
            if (keep) s_wl[wv][pos] = n;
            cnt += __popcll(b);
        }
        if (lane == 0) s_cnt[wv] = cnt;
    }
    __syncthreads();

    // ---- per-pixel evaluation: wave handles its half of the kept list ----
    const int cnt = s_cnt[wv];
    const int mid = (cnt + 1) >> 1;
    const int lo  = half ? mid : 0;
    const int hi  = half ? cnt : mid;

    const int px_i = wx0 + (lane & 7);
    const int py_i = wy0 + (lane >> 3);
    const float py = (float)py_i * (1.0f / 511.0f);
    const float px = (float)px_i * (1.0f / 511.0f);

    float sum = 0.0f;
    int i = lo;
    for (; i + 3 <= hi; i += 3) {
        const int n0 = s_wl[wv][i];
        const int n1 = s_wl[wv][i+1];
        const int n2 = s_wl[wv][i+2];
        const float c_0 = eval_one(py, px, s_f0[n0], s_f1[n0], s_f2[n0], s_lw[n0]);
        const float c_1 = eval_one(py, px, s_f0[n1], s_f1[n1], s_f2[n1], s_lw[n1]);
        const float c_2 = eval_one(py, px, s_f0[n2], s_f1[n2], s_f2[n2], s_lw[n2]);
        sum = ((sum + c_0) + c_1) + c_2;     // within-half ascending order
    }
    for (; i < hi; ++i) {
        const int n0 = s_wl[wv][i];
        sum += eval_one(py, px, s_f0[n0], s_f1[n0], s_f2[n0], s_lw[n0]);
    }

    if (half == 1) s_part[wv][lane] = sum;
    __syncthreads();
    if (half == 0) {
        const float total = sum + s_part[wv][lane];   // firstHalf + secondHalf
        out[py_i * 512 + px_i] = 1.0f - total;
    }
}

extern "C" void kernel_launch(void* const* d_in, const int* in_sizes, int n_in,
                              void* d_out, int out_size, void* d_ws, size_t ws_size,
                              hipStream_t stream) {
    const float* a  = (const float*)d_in[0];
    const float* b  = (const float*)d_in[1];
    const float* c  = (const float*)d_in[2];
    const float* lw = (const float*)d_in[3];
    const float* lc = (const float*)d_in[4];
    float* out = (float*)d_out;
    spline_render<<<dim3(1024), dim3(512), 0, stream>>>(a, b, c, lw, lc, out);
}

// Round 16
// 21.224 us; speedup vs baseline: 1.3229x; 1.0108x over previous
//
#include <hip/hip_runtime.h>
#include <math.h>

#define NSPL 128
#define SCALE 512.0f

__device__ __forceinline__ float fast_cbrt_pos(float x) {
    // x >= 0. Bit-hack seed (no log/exp) + 2 rcp-Newton steps; rel err ~1e-5.
    // Used where dist is 2nd-order-insensitive to root error (critical point
    // or clamped) -> value-neutral at bf16 granularity.
    unsigned int i = __float_as_uint(x);
    i = 0x2a510680u + (unsigned int)(((unsigned long long)i * 0xAAAAAAABull) >> 33);
    float r = __uint_as_float(i);
    float r2 = r * r;
    r = fmaf(0.66666667f, r, 0.33333333f * x * __builtin_amdgcn_rcpf(r2));
    r2 = r * r;
    r = fmaf(0.66666667f, r, 0.33333333f * x * __builtin_amdgcn_rcpf(r2));
    return (x < 1e-35f) ? 0.0f : r;
}

// cos/sin on [0, pi/3] via Taylor-Horner (abs err <= 4e-8). r13-proven.
__device__ __forceinline__ float cos_small(float v) {
    const float v2 = v * v;
    float p = -2.7557319e-7f;
    p = fmaf(p, v2, 2.4801587e-5f);
    p = fmaf(p, v2, -1.3888889e-3f);
    p = fmaf(p, v2, 4.1666667e-2f);
    p = fmaf(p, v2, -0.5f);
    return fmaf(p, v2, 1.0f);
}
__device__ __forceinline__ float sin_small(float v) {
    const float v2 = v * v;
    float p = 2.7557319e-6f;
    p = fmaf(p, v2, -1.9841270e-4f);
    p = fmaf(p, v2, 8.3333333e-3f);
    p = fmaf(p, v2, -0.16666667f);
    return v * fmaf(p, v2, 1.0f);
}

// One kept-spline contribution for one pixel (r13 numerics + bit-hack cbrt).
__device__ __forceinline__ float eval_one(
    float py, float px, const float4 f0, const float4 f1,
    const float4 f2, const float4 lw4)
{
    const float Ay = f0.z, Ax = f0.w;
    const float By = f1.x, Bx = f1.y;
    const float ca27 = f1.z, ca3 = f1.w;
    const float twoax2 = f2.x, third = f2.y, cbK = f2.z, r_nB = f2.w;

    const float Cy = py - f0.x, Cx = px - f0.y;
    const float CdB = Cy*By + Cx*Bx;
    const float CdA = Cy*Ay + Cx*Ax;
    const float cb = (CdB - cbK) * r_nB;
    const float cc = CdA * r_nB;

    const float p_  = cb - third;
    const float p3  = p_ * p_ * p_;
    const float q   = fmaf(ca27, fmaf(-9.0f, cb, twoax2), cc);
    const float d   = fmaf(q, q, p3 * (4.0f/27.0f));

    const bool sgl = d > 0.0f;
    // single-root via Cardano identity (r12-proven)
    const float sd = __builtin_amdgcn_sqrtf(fmaxf(d, 0.0f));
    const float mm = (fabsf(q) + sd) * 0.5f;
    const float r  = fast_cbrt_pos(mm);
    const float sg = (q > 0.0f) ? -1.0f : 1.0f;
    const float r0 = fmaf(sg, fmaf(-p_ * 0.33333334f, __builtin_amdgcn_rcpf(r), r), -ca3);

    float T0 = r0, T1 = r0;
    const unsigned long long bd = __ballot(sgl);
    if (bd != ~0ull) {  // trig branch: acos path libm-verbatim; cos/sin poly
        const float p3s = (fabsf(p3) > 1e-9f) ? p3 : 1e-9f;
        const float aarg = -sqrtf(fmaxf(-27.0f / p3s, 0.0f)) * q * 0.5f;
        const float v = acosf(fminf(fmaxf(aarg, -1.0f), 1.0f)) / 3.0f;
        const float m = cos_small(v);
        const float nn = sin_small(v) * 1.7320508075688772f;
        const float sp = sqrtf(fmaxf(-p_ / 3.0f, 0.0f));
        const float r1 = (m + m) * sp - ca3;
        const float r2 = (-nn - m) * sp - ca3;
        if (!sgl) { T0 = r1; T1 = r2; }
    }
    T0 = fminf(fmaxf(T0, 0.0f), 1.0f);
    T1 = fminf(fmaxf(T1, 0.0f), 1.0f);

    const float Dy = Ay + Ay, Dx = Ax + Ax;
    const float d1y = (Dy + By*T0)*T0 - Cy, d1x = (Dx + Bx*T0)*T0 - Cx;
    const float d2y = (Dy + By*T1)*T1 - Cy, d2x = (Dx + Bx*T1)*T1 - Cx;
    const float q1 = d1y*d1y + d1x*d1x;
    const float q2 = d2y*d2y + d2x*d2x;
    const float dist = __builtin_amdgcn_sqrtf(fminf(q1, q2));

    const float sarg = (lw4.z - dist) * lw4.y;
    const float e = __builtin_amdgcn_exp2f(sarg * -1.4426950408889634f);
    return lw4.x * __builtin_amdgcn_rcpf(1.0f + e);
}

// r13 structure: 1024 blocks x 256 threads; block = 16x16 px, wave = 8x8
// quadrant. Filter: ref-exact tile flag && ebox(E=2.45) && chord-band.
// Eval: unroll-3 independent chains; ascending sum order unchanged.
__global__ __launch_bounds__(256) void spline_render(
    const float* __restrict__ ga, const float* __restrict__ gb,
    const float* __restrict__ gc, const float* __restrict__ glw,
    const float* __restrict__ glc, float* __restrict__ out)
{
    __shared__ float4 s_f0[NSPL], s_f1[NSPL], s_f2[NSPL], s_eb[NSPL];
    __shared__ float4 s_sa[NSPL], s_sb[NSPL], s_sc[NSPL];
    __shared__ float4 s_lw[NSPL];
    __shared__ int    s_wl[4][NSPL];

    const int t  = threadIdx.x;
    const int bx = blockIdx.x & 31;   // 32 blocks across (16 px each)
    const int by = blockIdx.x >> 5;   // 32 blocks down  (16 px each)
    const float ty0 = (float)((by >> 2) << 6);   // enclosing 64x64 tile
    const float tx0 = (float)((bx >> 2) << 6);

    if (t < NSPL) {
        // ---- round-4 mask + constants, verbatim values ----
        const int n = t;
        const float ay  = ga[2*n],  ax  = ga[2*n+1];
        const float by_ = gb[2*n],  bx_ = gb[2*n+1];
        const float cy  = gc[2*n],  cx  = gc[2*n+1];
        const float w   = glw[n];

        float miy = fminf(ay, cy), may = fmaxf(ay, cy);
        float mix = fminf(ax, cx), maxx = fmaxf(ax, cx);
        bool cond = (by_ < miy) || (by_ > may) || (bx_ < mix) || (bx_ > maxx);
        float dny = ay - 2.0f*by_ + cy;
        float dnx = ax - 2.0f*bx_ + cx;
        bool dok = (fabsf(dny) > 1e-9f) && (fabsf(dnx) > 1e-9f);
        float tty = fminf(fmaxf((ay - by_) / ((fabsf(dny) > 1e-9f) ? dny : 1e-9f), 0.0f), 1.0f);
        float ttx = fminf(fmaxf((ax - bx_) / ((fabsf(dnx) > 1e-9f) ? dnx : 1e-9f), 0.0f), 1.0f);
        float sy = 1.0f - tty, sx = 1.0f - ttx;
        float qqy = sy*sy*ay + 2.0f*sy*tty*by_ + tty*tty*cy;
        float qqx = sx*sx*ax + 2.0f*sx*ttx*bx_ + ttx*ttx*cx;
        if (cond && dok) {
            miy = fminf(miy, qqy); may = fmaxf(may, qqy);
            mix = fminf(mix, qqx); maxx = fmaxf(maxx, qqx);
        }
        float mg = floorf(3.0f * w);   // MARGIN = 0
        float mi_py = fminf(fmaxf(floorf(miy*SCALE) - mg, 0.0f), 512.0f);
        float ma_py = fminf(fmaxf(ceilf (may*SCALE) + mg, 0.0f), 512.0f);
        float mi_px = fminf(fmaxf(floorf(mix*SCALE) - mg, 0.0f), 512.0f);
        float ma_px = fminf(fmaxf(ceilf (maxx*SCALE) + mg, 0.0f), 512.0f);
        bool flag = (ma_py > ty0) && (mi_py < ty0 + 64.0f)
                 && (ma_px > tx0) && (mi_px < tx0 + 64.0f);

        float bby = by_ + 1e-5f, bbx = bx_ + 1e-5f;
        float Ay = bby - ay, Ax = bbx - ax;
        float By = cy - bby - Ay, Bx = cx - bbx - Ax;
        float BdB = By*By + Bx*Bx;
        float nB  = -BdB;
        float AdB = Ay*By + Ax*Bx;
        float ca  = (-3.0f * AdB) / nB;
        float ax2 = ca * ca;
        s_f0[n] = make_float4(ay, ax, Ay, Ax);
        s_f1[n] = make_float4(By, Bx, ca / 27.0f, ca / 3.0f);
        s_f2[n] = make_float4(2.0f * ax2, ax2 / 3.0f,
                              2.0f * (Ay*Ay + Ax*Ax), 1.0f / nB);
        s_lw[n] = make_float4(glc[n], 6.0f / w, w, 0.0f);

        // expanded bbox, E = 2.45 band: dropped contributions < 1.7e-4 each
        float E = fmaf(2.45f * 512.0f, w, 3.0f);
        s_eb[n] = flag ? make_float4(mi_py - E, ma_py + E, mi_px - E, ma_px + E)
                       : make_float4(1e30f, -1e30f, 1e30f, -1e30f);

        // chord-band data: curve(t) = a + 2At + Bt^2, t=0,.25,.5,.75,1 in px;
        // per-quarter-chord deviation <= |B|*511/64.
        float q0y = ay * 511.0f,                                   q0x = ax * 511.0f;
        float q1y = (ay + 2.0f*Ay*0.25f + By*0.0625f) * 511.0f,    q1x = (ax + 2.0f*Ax*0.25f + Bx*0.0625f) * 511.0f;
        float q2y = (ay + Ay + By*0.25f) * 511.0f,                 q2x = (ax + Ax + Bx*0.25f) * 511.0f;
        float q3y = (ay + 2.0f*Ay*0.75f + By*0.5625f) * 511.0f,    q3x = (ax + 2.0f*Ax*0.75f + Bx*0.5625f) * 511.0f;
        float q4y = (ay + 2.0f*Ay + By) * 511.0f,                  q4x = (ax + 2.0f*Ax + Bx) * 511.0f;
        float dev = __builtin_amdgcn_sqrtf(BdB) * (511.0f / 64.0f);
        float R   = E + dev + 6.0f;   // + halfdiag(4.95) + slop
        s_sa[n] = make_float4(q0y, q0x, q1y, q1x);
        s_sb[n] = make_float4(q2y, q2x, q3y, q3x);
        s_sc[n] = make_float4(q4y, q4x, R * R, 0.0f);
    }
    __syncthreads();

    // ---- per-wave 8x8-quadrant filter (ascending, order-preserving) ----
    const int lane = t & 63;
    const int wv   = t >> 6;
    const int wx0 = (bx << 4) + ((wv & 1) << 3);
    const int wy0 = (by << 4) + ((wv >> 1) << 3);
    const float wy0f = (float)wy0, wx0f = (float)wx0;
    const float cyp = wy0f + 3.5f, cxp = wx0f + 3.5f;   // region center (px)

    int cnt = 0;
    #pragma unroll
    for (int h = 0; h < 2; ++h) {
        const int n = (h << 6) + lane;
        const float4 eb = s_eb[n];
        bool keep = (eb.y > wy0f) && (eb.x < wy0f + 8.0f)
                 && (eb.w > wx0f) && (eb.z < wx0f + 8.0f);
        if (keep) {
            const float4 sa = s_sa[n];
            const float4 sb = s_sb[n];
            const float4 sc = s_sc[n];
            float best = 1e30f;
            float py0 = sa.x, px0 = sa.y;
            #pragma unroll
            for (int s = 0; s < 4; ++s) {
                const float py1 = (s == 0) ? sa.z : (s == 1) ? sb.x : (s == 2) ? sb.z : sc.x;
                const float px1 = (s == 0) ? sa.w : (s == 1) ? sb.y : (s == 2) ? sb.w : sc.y;
                const float vy = py1 - py0, vx = px1 - px0;
                const float wy = cyp - py0, wx = cxp - px0;
                const float vv = fmaxf(vy*vy + vx*vx, 1e-12f);
                const float tt = fminf(fmaxf((wy*vy + wx*vx) * __builtin_amdgcn_rcpf(vv), 0.0f), 1.0f);
                const float dy = wy - tt*vy, dx = wx - tt*vx;
                best = fminf(best, dy*dy + dx*dx);
                py0 = py1; px0 = px1;
            }
            keep = best <= sc.z;
        }
        const unsigned long long b = __ballot(keep);
        const int pos = cnt + __popcll(b & ((1ull << lane) - 1ull));
        if (keep) s_wl[wv][pos] = n;
        cnt += __popcll(b);
    }

    // ---- per-pixel evaluation, unroll-3 (independent chains; same sum order) ----
    const int px_i = wx0 + (lane & 7);
    const int py_i = wy0 + (lane >> 3);
    const float py = (float)py_i * (1.0f / 511.0f);
    const float px = (float)px_i * (1.0f / 511.0f);

    float sum = 0.0f;
    int i = 0;
    for (; i + 3 <= cnt; i += 3) {
        const int n0 = s_wl[wv][i];
        const int n1 = s_wl[wv][i+1];
        const int n2 = s_wl[wv][i+2];
        const float c_0 = eval_one(py, px, s_f0[n0], s_f1[n0], s_f2[n0], s_lw[n0]);
        const float c_1 = eval_one(py, px, s_f0[n1], s_f1[n1], s_f2[n1], s_lw[n1]);
        const float c_2 = eval_one(py, px, s_f0[n2], s_f1[n2], s_f2[n2], s_lw[n2]);
        sum = ((sum + c_0) + c_1) + c_2;     // ascending order preserved
    }
    for (; i < cnt; ++i) {
        const int n0 = s_wl[wv][i];
        sum += eval_one(py, px, s_f0[n0], s_f1[n0], s_f2[n0], s_lw[n0]);
    }

    out[py_i * 512 + px_i] = 1.0f - sum;
}

extern "C" void kernel_launch(void* const* d_in, const int* in_sizes, int n_in,
                              void* d_out, int out_size, void* d_ws, size_t ws_size,
                              hipStream_t stream) {
    const float* a  = (const float*)d_in[0];
    const float* b  = (const float*)d_in[1];
    const float* c  = (const float*)d_in[2];
    const float* lw = (const float*)d_in[3];
    const float* lc = (const float*)d_in[4];
    float* out = (float*)d_out;
    spline_render<<<dim3(1024), dim3(256), 0, stream>>>(a, b, c, lw, lc, out);
}

// Round 17
// 20.593 us; speedup vs baseline: 1.3634x; 1.0306x over previous
//
#include <hip/hip_runtime.h>
#include <math.h>

#define NSPL 128
#define SCALE 512.0f

__device__ __forceinline__ float fast_cbrt_pos(float x) {
    // x >= 0. Bit-hack seed (no log/exp) + 2 rcp-Newton steps; rel err ~1e-5.
    unsigned int i = __float_as_uint(x);
    i = 0x2a510680u + (unsigned int)(((unsigned long long)i * 0xAAAAAAABull) >> 33);
    float r = __uint_as_float(i);
    float r2 = r * r;
    r = fmaf(0.66666667f, r, 0.33333333f * x * __builtin_amdgcn_rcpf(r2));
    r2 = r * r;
    r = fmaf(0.66666667f, r, 0.33333333f * x * __builtin_amdgcn_rcpf(r2));
    return (x < 1e-35f) ? 0.0f : r;
}

// cos/sin on [0, pi/3] via Taylor-Horner (abs err <= 4e-8). r13-proven.
__device__ __forceinline__ float cos_small(float v) {
    const float v2 = v * v;
    float p = -2.7557319e-7f;
    p = fmaf(p, v2, 2.4801587e-5f);
    p = fmaf(p, v2, -1.3888889e-3f);
    p = fmaf(p, v2, 4.1666667e-2f);
    p = fmaf(p, v2, -0.5f);
    return fmaf(p, v2, 1.0f);
}
__device__ __forceinline__ float sin_small(float v) {
    const float v2 = v * v;
    float p = 2.7557319e-6f;
    p = fmaf(p, v2, -1.9841270e-4f);
    p = fmaf(p, v2, 8.3333333e-3f);
    p = fmaf(p, v2, -0.16666667f);
    return v * fmaf(p, v2, 1.0f);
}

// One kept-spline contribution for one pixel (r16 numerics, bit-identical).
__device__ __forceinline__ float eval_one(
    float py, float px, const float4 f0, const float4 f1,
    const float4 f2, const float4 lw4)
{
    const float Ay = f0.z, Ax = f0.w;
    const float By = f1.x, Bx = f1.y;
    const float ca27 = f1.z, ca3 = f1.w;
    const float twoax2 = f2.x, third = f2.y, cbK = f2.z, r_nB = f2.w;

    const float Cy = py - f0.x, Cx = px - f0.y;
    const float CdB = Cy*By + Cx*Bx;
    const float CdA = Cy*Ay + Cx*Ax;
    const float cb = (CdB - cbK) * r_nB;
    const float cc = CdA * r_nB;

    const float p_  = cb - third;
    const float p3  = p_ * p_ * p_;
    const float q   = fmaf(ca27, fmaf(-9.0f, cb, twoax2), cc);
    const float d   = fmaf(q, q, p3 * (4.0f/27.0f));

    const bool sgl = d > 0.0f;
    // single-root via Cardano identity (r12-proven)
    const float sd = __builtin_amdgcn_sqrtf(fmaxf(d, 0.0f));
    const float mm = (fabsf(q) + sd) * 0.5f;
    const float r  = fast_cbrt_pos(mm);
    const float sg = (q > 0.0f) ? -1.0f : 1.0f;
    const float r0 = fmaf(sg, fmaf(-p_ * 0.33333334f, __builtin_amdgcn_rcpf(r), r), -ca3);

    float T0 = r0, T1 = r0;
    const unsigned long long bd = __ballot(sgl);
    if (bd != ~0ull) {  // trig branch: acos path libm-verbatim; cos/sin poly
        const float p3s = (fabsf(p3) > 1e-9f) ? p3 : 1e-9f;
        const float aarg = -sqrtf(fmaxf(-27.0f / p3s, 0.0f)) * q * 0.5f;
        const float v = acosf(fminf(fmaxf(aarg, -1.0f), 1.0f)) / 3.0f;
        const float m = cos_small(v);
        const float nn = sin_small(v) * 1.7320508075688772f;
        const float sp = sqrtf(fmaxf(-p_ / 3.0f, 0.0f));
        const float r1 = (m + m) * sp - ca3;
        const float r2 = (-nn - m) * sp - ca3;
        if (!sgl) { T0 = r1; T1 = r2; }
    }
    T0 = fminf(fmaxf(T0, 0.0f), 1.0f);
    T1 = fminf(fmaxf(T1, 0.0f), 1.0f);

    const float Dy = Ay + Ay, Dx = Ax + Ax;
    const float d1y = (Dy + By*T0)*T0 - Cy, d1x = (Dx + Bx*T0)*T0 - Cx;
    const float d2y = (Dy + By*T1)*T1 - Cy, d2x = (Dx + Bx*T1)*T1 - Cx;
    const float q1 = d1y*d1y + d1x*d1x;
    const float q2 = d2y*d2y + d2x*d2x;
    const float dist = __builtin_amdgcn_sqrtf(fminf(q1, q2));

    const float sarg = (lw4.z - dist) * lw4.y;
    const float e = __builtin_amdgcn_exp2f(sarg * -1.4426950408889634f);
    return lw4.x * __builtin_amdgcn_rcpf(1.0f + e);
}

// r16 structure: 1024 blocks x 256 threads; block = 16x16 px, wave = 8x8
// quadrant. Filter: ref-exact tile flag && ebox(E=2.45) && 8-segment
// divide-free chord-band (dev/4, R = E + dev/4 + 5). Eval: r16-verbatim.
__global__ __launch_bounds__(256) void spline_render(
    const float* __restrict__ ga, const float* __restrict__ gb,
    const float* __restrict__ gc, const float* __restrict__ glw,
    const float* __restrict__ glc, float* __restrict__ out)
{
    __shared__ float4 s_f0[NSPL], s_f1[NSPL], s_f2[NSPL], s_eb[NSPL];
    __shared__ float4 s_lw[NSPL];
    __shared__ float  s_py9[9][NSPL], s_px9[9][NSPL];   // conflict-free lane-indexed
    __shared__ float  s_R2[NSPL];
    __shared__ int    s_wl[4][NSPL];

    const int t  = threadIdx.x;
    const int bx = blockIdx.x & 31;   // 32 blocks across (16 px each)
    const int by = blockIdx.x >> 5;   // 32 blocks down  (16 px each)
    const float ty0 = (float)((by >> 2) << 6);   // enclosing 64x64 tile
    const float tx0 = (float)((bx >> 2) << 6);

    if (t < NSPL) {
        // ---- round-4 mask + constants, verbatim values ----
        const int n = t;
        const float ay  = ga[2*n],  ax  = ga[2*n+1];
        const float by_ = gb[2*n],  bx_ = gb[2*n+1];
        const float cy  = gc[2*n],  cx  = gc[2*n+1];
        const float w   = glw[n];

        float miy = fminf(ay, cy), may = fmaxf(ay, cy);
        float mix = fminf(ax, cx), maxx = fmaxf(ax, cx);
        bool cond = (by_ < miy) || (by_ > may) || (bx_ < mix) || (bx_ > maxx);
        float dny = ay - 2.0f*by_ + cy;
        float dnx = ax - 2.0f*bx_ + cx;
        bool dok = (fabsf(dny) > 1e-9f) && (fabsf(dnx) > 1e-9f);
        float tty = fminf(fmaxf((ay - by_) / ((fabsf(dny) > 1e-9f) ? dny : 1e-9f), 0.0f), 1.0f);
        float ttx = fminf(fmaxf((ax - bx_) / ((fabsf(dnx) > 1e-9f) ? dnx : 1e-9f), 0.0f), 1.0f);
        float sy = 1.0f - tty, sx = 1.0f - ttx;
        float qqy = sy*sy*ay + 2.0f*sy*tty*by_ + tty*tty*cy;
        float qqx = sx*sx*ax + 2.0f*sx*ttx*bx_ + ttx*ttx*cx;
        if (cond && dok) {
            miy = fminf(miy, qqy); may = fmaxf(may, qqy);
            mix = fminf(mix, qqx); maxx = fmaxf(maxx, qqx);
        }
        float mg = floorf(3.0f * w);   // MARGIN = 0
        float mi_py = fminf(fmaxf(floorf(miy*SCALE) - mg, 0.0f), 512.0f);
        float ma_py = fminf(fmaxf(ceilf (may*SCALE) + mg, 0.0f), 512.0f);
        float mi_px = fminf(fmaxf(floorf(mix*SCALE) - mg, 0.0f), 512.0f);
        float ma_px = fminf(fmaxf(ceilf (maxx*SCALE) + mg, 0.0f), 512.0f);
        bool flag = (ma_py > ty0) && (mi_py < ty0 + 64.0f)
                 && (ma_px > tx0) && (mi_px < tx0 + 64.0f);

        float bby = by_ + 1e-5f, bbx = bx_ + 1e-5f;
        float Ay = bby - ay, Ax = bbx - ax;
        float By = cy - bby - Ay, Bx = cx - bbx - Ax;
        float BdB = By*By + Bx*Bx;
        float nB  = -BdB;
        float AdB = Ay*By + Ax*Bx;
        float ca  = (-3.0f * AdB) / nB;
        float ax2 = ca * ca;
        s_f0[n] = make_float4(ay, ax, Ay, Ax);
        s_f1[n] = make_float4(By, Bx, ca / 27.0f, ca / 3.0f);
        s_f2[n] = make_float4(2.0f * ax2, ax2 / 3.0f,
                              2.0f * (Ay*Ay + Ax*Ax), 1.0f / nB);
        s_lw[n] = make_float4(glc[n], 6.0f / w, w, 0.0f);

        // expanded bbox, E = 2.45 band (r16-proven: dropped < 1.7e-4 each)
        float E = fmaf(2.45f * 512.0f, w, 3.0f);
        s_eb[n] = flag ? make_float4(mi_py - E, ma_py + E, mi_px - E, ma_px + E)
                       : make_float4(1e30f, -1e30f, 1e30f, -1e30f);

        // 8-segment polyline: curve(t)=a+2At+Bt^2 at t=k/8, px coords (x511).
        // per-eighth-chord deviation <= |B|*511/256.
        #pragma unroll
        for (int k = 0; k <= 8; ++k) {
            const float tk = (float)k * 0.125f;
            s_py9[k][n] = fmaf(fmaf(By, tk, Ay + Ay), tk, ay) * 511.0f;
            s_px9[k][n] = fmaf(fmaf(Bx, tk, Ax + Ax), tk, ax) * 511.0f;
        }
        float dev = __builtin_amdgcn_sqrtf(BdB) * (511.0f / 256.0f);
        float R = E + dev + 5.0f;   // halfdiag(4.95) + slop
        s_R2[n] = R * R;
    }
    __syncthreads();

    // ---- per-wave 8x8-quadrant filter (ascending, order-preserving) ----
    const int lane = t & 63;
    const int wv   = t >> 6;
    const int wx0 = (bx << 4) + ((wv & 1) << 3);
    const int wy0 = (by << 4) + ((wv >> 1) << 3);
    const float wy0f = (float)wy0, wx0f = (float)wx0;
    const float cyp = wy0f + 3.5f, cxp = wx0f + 3.5f;   // region center (px)

    int cnt = 0;
    #pragma unroll
    for (int h = 0; h < 2; ++h) {
        const int n = (h << 6) + lane;
        const float4 eb = s_eb[n];
        bool keep = (eb.y > wy0f) && (eb.x < wy0f + 8.0f)
                 && (eb.w > wx0f) && (eb.z < wx0f + 8.0f);
        if (keep) {
            // divide-free point-to-polyline <= R test (8 segments)
            const float R2 = s_R2[n];
            float p0y = s_py9[0][n], p0x = s_px9[0][n];
            float wy = cyp - p0y, wx = cxp - p0x;
            float ww = wy*wy + wx*wx;
            bool inside = false;
            #pragma unroll
            for (int s = 1; s <= 8; ++s) {
                const float p1y = s_py9[s][n], p1x = s_px9[s][n];
                const float vy = p1y - p0y, vx = p1x - p0x;
                const float w1y = wy - vy,  w1x = wx - vx;
                const float vv = vy*vy + vx*vx;
                const float wvd = wy*vy + wx*vx;
                const float w1w1 = w1y*w1y + w1x*w1x;
                // min_{t in [0,1]} |w - t v|^2 <= R^2, divide-free:
                const bool in_s = (wvd <= 0.0f) ? (ww <= R2)
                               : (wvd >= vv)   ? (w1w1 <= R2)
                               : (fmaf(ww, vv, -wvd*wvd) <= R2 * vv);
                inside = inside || in_s;
                p0y = p1y; p0x = p1x;
                wy = w1y; wx = w1x; ww = w1w1;
            }
            keep = inside;
        }
        const unsigned long long b = __ballot(keep);
        const int pos = cnt + __popcll(b & ((1ull << lane) - 1ull));
        if (keep) s_wl[wv][pos] = n;
        cnt += __popcll(b);
    }

    // ---- per-pixel evaluation, unroll-3 (independent chains; same sum order) ----
    const int px_i = wx0 + (lane & 7);
    const int py_i = wy0 + (lane >> 3);
    const float py = (float)py_i * (1.0f / 511.0f);
    const float px = (float)px_i * (1.0f / 511.0f);

    float sum = 0.0f;
    int i = 0;
    for (; i + 3 <= cnt; i += 3) {
        const int n0 = s_wl[wv][i];
        const int n1 = s_wl[wv][i+1];
        const int n2 = s_wl[wv][i+2];
        const float c_0 = eval_one(py, px, s_f0[n0], s_f1[n0], s_f2[n0], s_lw[n0]);
        const float c_1 = eval_one(py, px, s_f0[n1], s_f1[n1], s_f2[n1], s_lw[n1]);
        const float c_2 = eval_one(py, px, s_f0[n2], s_f1[n2], s_f2[n2], s_lw[n2]);
        sum = ((sum + c_0) + c_1) + c_2;     // ascending order preserved
    }
    for (; i < cnt; ++i) {
        const int n0 = s_wl[wv][i];
        sum += eval_one(py, px, s_f0[n0], s_f1[n0], s_f2[n0], s_lw[n0]);
    }

    out[py_i * 512 + px_i] = 1.0f - sum;
}

extern "C" void kernel_launch(void* const* d_in, const int* in_sizes, int n_in,
                              void* d_out, int out_size, void* d_ws, size_t ws_size,
                              hipStream_t stream) {
    const float* a  = (const float*)d_in[0];
    const float* b  = (const float*)d_in[1];
    const float* c  = (const float*)d_in[2];
    const float* lw = (const float*)d_in[3];
    const float* lc = (const float*)d_in[4];
    float* out = (float*)d_out;
    spline_render<<<dim3(1024), dim3(256), 0, stream>>>(a, b, c, lw, lc, out);
}